// Round 2
// baseline (484.777 us; speedup 1.0000x reference)
//
#include <hip/hip_runtime.h>
#include <hip/hip_bf16.h>

// out[i,f] = a[f]*x[i,f] + b[f], a/b per group of 32 features.
// x: [2097152, 128] fp32 = 1 GiB in + 1 GiB out -> pure HBM-streaming.
// float4 index i -> group g = ((i % 32) >> 3); grid-stride is a multiple
// of 32 so g is loop-invariant per thread (scale/shift hoisted).
// Non-temporal loads/stores (streams >> L3, zero reuse) + 4x unroll for MLP.

typedef float f4 __attribute__((ext_vector_type(4)));

__global__ __launch_bounds__(256) void normalize_kernel(
    const f4* __restrict__ x,
    const float* __restrict__ x_min,
    const float* __restrict__ x_max,
    const float* __restrict__ u,
    const float* __restrict__ l,
    f4* __restrict__ out,
    long long n4)
{
    const long long stride = (long long)gridDim.x * blockDim.x;
    long long i = (long long)blockIdx.x * blockDim.x + threadIdx.x;

    const int g = (int)((i & 31) >> 3);
    const float s = (u[g] - l[g]) / (x_max[g] - x_min[g]);
    const float b = l[g] - x_min[g] * s;

    // Main loop: 4 independent loads in flight, then compute, then 4 stores.
    for (; i + 3 * stride < n4; i += 4 * stride) {
        f4 v0 = __builtin_nontemporal_load(&x[i]);
        f4 v1 = __builtin_nontemporal_load(&x[i + stride]);
        f4 v2 = __builtin_nontemporal_load(&x[i + 2 * stride]);
        f4 v3 = __builtin_nontemporal_load(&x[i + 3 * stride]);
        f4 o0, o1, o2, o3;
        #pragma unroll
        for (int k = 0; k < 4; ++k) {
            o0[k] = fmaf(s, v0[k], b);
            o1[k] = fmaf(s, v1[k], b);
            o2[k] = fmaf(s, v2[k], b);
            o3[k] = fmaf(s, v3[k], b);
        }
        __builtin_nontemporal_store(o0, &out[i]);
        __builtin_nontemporal_store(o1, &out[i + stride]);
        __builtin_nontemporal_store(o2, &out[i + 2 * stride]);
        __builtin_nontemporal_store(o3, &out[i + 3 * stride]);
    }
    // Tail (not taken for the bench shape: n4 = 128 * stride exactly).
    for (; i < n4; i += stride) {
        f4 v = __builtin_nontemporal_load(&x[i]);
        f4 o;
        #pragma unroll
        for (int k = 0; k < 4; ++k) o[k] = fmaf(s, v[k], b);
        __builtin_nontemporal_store(o, &out[i]);
    }
}

extern "C" void kernel_launch(void* const* d_in, const int* in_sizes, int n_in,
                              void* d_out, int out_size, void* d_ws, size_t ws_size,
                              hipStream_t stream) {
    const f4*    x     = (const f4*)d_in[0];
    const float* x_min = (const float*)d_in[1];
    const float* x_max = (const float*)d_in[2];
    const float* u     = (const float*)d_in[3];
    const float* l     = (const float*)d_in[4];
    f4* out = (f4*)d_out;

    const long long n4 = (long long)out_size / 4;

    const int block = 256;
    // 2048 blocks = 8 blocks/CU on 256 CUs (32 waves/CU).
    int grid = 2048;
    long long needed = (n4 + block - 1) / block;
    if (needed < grid) grid = (int)needed;

    normalize_kernel<<<grid, block, 0, stream>>>(x, x_min, x_max, u, l, out, n4);
}

// Round 3
// 468.046 us; speedup vs baseline: 1.0357x; 1.0357x over previous
//
#include <hip/hip_runtime.h>
#include <hip/hip_bf16.h>

// out[i,f] = a[f]*x[i,f] + b[f], a/b per group of 32 features.
// x: [2097152, 128] fp32 = 1 GiB in + 1 GiB out -> pure HBM-streaming.
// float4 index i -> group g = ((i % 32) >> 3); grid-stride is a multiple
// of 32 so g is loop-invariant per thread (scale/shift hoisted).
// Round 3: 4-deep unroll for loads-in-flight, NO non-temporal (nt regressed
// Round 2: 443 -> 485 us; L2-cached streams are faster on gfx950).

typedef float f4 __attribute__((ext_vector_type(4)));

__global__ __launch_bounds__(256) void normalize_kernel(
    const f4* __restrict__ x,
    const float* __restrict__ x_min,
    const float* __restrict__ x_max,
    const float* __restrict__ u,
    const float* __restrict__ l,
    f4* __restrict__ out,
    long long n4)
{
    const long long stride = (long long)gridDim.x * blockDim.x;
    long long i = (long long)blockIdx.x * blockDim.x + threadIdx.x;

    const int g = (int)((i & 31) >> 3);
    const float s = (u[g] - l[g]) / (x_max[g] - x_min[g]);
    const float b = l[g] - x_min[g] * s;

    // Main loop: 4 independent loads in flight, then compute, then 4 stores.
    for (; i + 3 * stride < n4; i += 4 * stride) {
        f4 v0 = x[i];
        f4 v1 = x[i + stride];
        f4 v2 = x[i + 2 * stride];
        f4 v3 = x[i + 3 * stride];
        f4 o0, o1, o2, o3;
        #pragma unroll
        for (int k = 0; k < 4; ++k) {
            o0[k] = fmaf(s, v0[k], b);
            o1[k] = fmaf(s, v1[k], b);
            o2[k] = fmaf(s, v2[k], b);
            o3[k] = fmaf(s, v3[k], b);
        }
        out[i]              = o0;
        out[i + stride]     = o1;
        out[i + 2 * stride] = o2;
        out[i + 3 * stride] = o3;
    }
    // Tail (not taken for the bench shape: n4 = 128 * stride exactly).
    for (; i < n4; i += stride) {
        f4 v = x[i];
        f4 o;
        #pragma unroll
        for (int k = 0; k < 4; ++k) o[k] = fmaf(s, v[k], b);
        out[i] = o;
    }
}

extern "C" void kernel_launch(void* const* d_in, const int* in_sizes, int n_in,
                              void* d_out, int out_size, void* d_ws, size_t ws_size,
                              hipStream_t stream) {
    const f4*    x     = (const f4*)d_in[0];
    const float* x_min = (const float*)d_in[1];
    const float* x_max = (const float*)d_in[2];
    const float* u     = (const float*)d_in[3];
    const float* l     = (const float*)d_in[4];
    f4* out = (f4*)d_out;

    const long long n4 = (long long)out_size / 4;

    const int block = 256;
    // 2048 blocks = 8 blocks/CU on 256 CUs (32 waves/CU).
    int grid = 2048;
    long long needed = (n4 + block - 1) / block;
    if (needed < grid) grid = (int)needed;

    normalize_kernel<<<grid, block, 0, stream>>>(x, x_min, x_max, u, l, out, n4);
}

// Round 4
// 396.323 us; speedup vs baseline: 1.2232x; 1.1810x over previous
//
#include <hip/hip_runtime.h>
#include <hip/hip_bf16.h>

// out[i,f] = a[f]*x[i,f] + b[f], a/b per group of 32 features.
// x: [2097152, 128] fp32 = 1 GiB in + 1 GiB out -> pure HBM-streaming.
// Round 4: ADJACENT 4x unroll — each block handles a contiguous 16 KiB
// chunk per iteration (each wave: 4 KiB contiguous burst of loads, then
// 4 KiB contiguous burst of stores). Round 2 (nt) and Round 3
// (stride-separated unroll) both regressed vs the simple loop (443 us);
// this keeps unroll depth but fixes burst adjacency.

typedef float f4 __attribute__((ext_vector_type(4)));

#define BLOCK 256

__global__ __launch_bounds__(BLOCK) void normalize_kernel(
    const f4* __restrict__ x,
    const float* __restrict__ x_min,
    const float* __restrict__ x_max,
    const float* __restrict__ u,
    const float* __restrict__ l,
    f4* __restrict__ out,
    long long n4)
{
    const int tid = threadIdx.x;
    const long long block_chunk = 4LL * BLOCK;                    // 1024 f4 / block-iter
    const long long gstride = (long long)gridDim.x * block_chunk; // > 768 always
    long long base = (long long)blockIdx.x * block_chunk + tid;

    // index = base + k*256; base = tid + multiples of 1024 -> (idx & 31) == (tid & 31):
    // group is invariant per thread, hoist scale/shift.
    const int g = (tid & 31) >> 3;
    const float s = (u[g] - l[g]) / (x_max[g] - x_min[g]);
    const float b = l[g] - x_min[g] * s;

    for (; base + 3 * BLOCK < n4; base += gstride) {
        f4 v0 = x[base];
        f4 v1 = x[base + 1 * BLOCK];
        f4 v2 = x[base + 2 * BLOCK];
        f4 v3 = x[base + 3 * BLOCK];
        f4 o0, o1, o2, o3;
        #pragma unroll
        for (int k = 0; k < 4; ++k) {
            o0[k] = fmaf(s, v0[k], b);
            o1[k] = fmaf(s, v1[k], b);
            o2[k] = fmaf(s, v2[k], b);
            o3[k] = fmaf(s, v3[k], b);
        }
        out[base]             = o0;
        out[base + 1 * BLOCK] = o1;
        out[base + 2 * BLOCK] = o2;
        out[base + 3 * BLOCK] = o3;
    }
    // Tail within the last partial window (not taken for the bench shape:
    // n4 = 64Mi is an exact multiple of gstride for grid=2048).
    for (long long j = base; j < n4; j += BLOCK) {
        f4 v = x[j];
        f4 o;
        #pragma unroll
        for (int k = 0; k < 4; ++k) o[k] = fmaf(s, v[k], b);
        out[j] = o;
    }
}

extern "C" void kernel_launch(void* const* d_in, const int* in_sizes, int n_in,
                              void* d_out, int out_size, void* d_ws, size_t ws_size,
                              hipStream_t stream) {
    const f4*    x     = (const f4*)d_in[0];
    const float* x_min = (const float*)d_in[1];
    const float* x_max = (const float*)d_in[2];
    const float* u     = (const float*)d_in[3];
    const float* l     = (const float*)d_in[4];
    f4* out = (f4*)d_out;

    const long long n4 = (long long)out_size / 4;

    // 2048 blocks = 8 blocks/CU on 256 CUs; each block-iter covers 16 KiB.
    int grid = 2048;
    long long needed = (n4 + 4LL * BLOCK - 1) / (4LL * BLOCK);
    if (needed < grid) grid = (int)(needed > 0 ? needed : 1);

    normalize_kernel<<<grid, BLOCK, 0, stream>>>(x, x_min, x_max, u, l, out, n4);
}